// Round 1
// baseline (2873.129 us; speedup 1.0000x reference)
//
#include <hip/hip_runtime.h>

constexpr int BB = 4, NN = 8192, KNB = 20;
constexpr int BN_ = BB * NN; // 32768
constexpr float EPSV = 1e-5f;

// ---------------- workspace layout (float offsets) ----------------
constexpr size_t OFF_MODE  = 0;
constexpr size_t OFF_FLAGS = 64;                    // int[4*8192]
constexpr size_t OFF_M0 = OFF_FLAGS + BN_;          // 32832  (zero region start)
constexpr size_t OFF_S0 = OFF_M0 + 12;
constexpr size_t OFF_M1 = OFF_S0 + 144;
constexpr size_t OFF_S1 = OFF_M1 + 64;
constexpr size_t OFF_M2 = OFF_S1 + 64 * 64;
constexpr size_t OFF_S2 = OFF_M2 + 64;
constexpr size_t OFF_M3 = OFF_S2 + 64 * 64;
constexpr size_t OFF_S3 = OFF_M3 + 64;
constexpr size_t OFF_M4 = OFF_S3 + 64 * 64;
constexpr size_t OFF_S4 = OFF_M4 + 128;
constexpr size_t OFF_POOL = OFF_S4 + 128 * 128;
constexpr size_t OFF_ZEND = OFF_POOL + BB * 1024;   // zero region end
constexpr size_t OFF_A1 = OFF_ZEND;
constexpr size_t OFF_B1 = OFF_A1 + 64;
constexpr size_t OFF_A2 = OFF_B1 + 64;
constexpr size_t OFF_B2 = OFF_A2 + 64;
constexpr size_t OFF_A3 = OFF_B2 + 64;
constexpr size_t OFF_B3 = OFF_A3 + 64;
constexpr size_t OFF_A4 = OFF_B3 + 64;
constexpr size_t OFF_B4 = OFF_A4 + 128;
constexpr size_t OFF_A5 = OFF_B4 + 128;
constexpr size_t OFF_B5 = OFF_A5 + 1024;
constexpr size_t OFF_SH = OFF_B5 + 1024;            // 4*512
constexpr size_t OFF_WT_RAW = OFF_SH + BB * 512;
constexpr size_t OFF_WT = (OFF_WT_RAW + 63) & ~size_t(63);  // wT5 [128][1024]
constexpr size_t OFF_H0_RAW = OFF_WT + 1024 * 128;
constexpr size_t OFF_H0 = (OFF_H0_RAW + 63) & ~size_t(63);  // [4][12][8192]
constexpr size_t OFF_H1 = OFF_H0 + (size_t)BB * 12 * NN;    // [4][64][8192]
constexpr size_t OFF_H2 = OFF_H1 + (size_t)BB * 64 * NN;    // [4][64][8192]
constexpr size_t OFF_H3 = OFF_H1;                           // alias (h1 dead)
constexpr size_t OFF_H4 = OFF_H2 + (size_t)BB * 64 * NN;    // [4][128][8192]
constexpr size_t WS_FLOATS = OFF_H4 + (size_t)BB * 128 * NN;

// ---------------- prep: detect bool storage + canonicalize flags ----------------
__global__ void k_prep(const int* __restrict__ li32, int* __restrict__ mode,
                       int* __restrict__ flags) {
  __shared__ int s_mode;
  const int t = threadIdx.x;
  if (t == 0) s_mode = 0;
  __syncthreads();
  // 8192 int32 = 32768 bytes: in-bounds under both interpretations.
  for (int i = t; i < 8192; i += 256)
    if (((const unsigned int*)li32)[i] > 1u) atomicOr(&s_mode, 1);
  __syncthreads();
  const int md = s_mode;   // 1 => stored as bytes, 0 => stored as int32
  if (t == 0) *mode = md;
  const unsigned char* p8 = (const unsigned char*)li32;
  for (int i = t; i < BN_; i += 256)
    flags[i] = md ? (p8[i] != 0 ? 1 : 0) : (li32[i] != 0 ? 1 : 0);
}

// ---------------- kNN + covariance -> h0 [4][12][8192] ----------------
__global__ __launch_bounds__(256) void k_knn(const float* __restrict__ x,
                                             const int* __restrict__ flags,
                                             float* __restrict__ h0) {
  const int blk  = blockIdx.x;        // 512 blocks = 4 batches * 128 tiles
  const int b    = blk >> 7;
  const int tile = blk & 127;
  const int t    = threadIdx.x;
  const int lane = t & 63;
  const int q    = __builtin_amdgcn_readfirstlane(t >> 6);  // m-quarter per wave
  const int n    = tile * 64 + lane;

  const float* __restrict__ xb = x + (size_t)b * 3 * NN;
  const int* __restrict__ fl = flags + b * NN;

  const float xn0 = xb[n], xn1 = xb[NN + n], xn2 = xb[2 * NN + n];

  float tk[KNB];
#pragma unroll
  for (int i = 0; i < KNB; ++i) tk[i] = 3.0e38f;

  const int mlo = q * (NN / 4), mhi = mlo + NN / 4;
  for (int m = mlo; m < mhi; ++m) {
    if (fl[m] == 0) continue;                       // wave-uniform skip
    const float d0 = xb[m] - xn0;
    const float d1 = xb[NN + m] - xn1;
    const float d2 = xb[2 * NN + m] - xn2;
    float d = __builtin_fmaf(d0, d0, __builtin_fmaf(d1, d1, d2 * d2));
    if (d < tk[KNB - 1]) {                          // sorted-insert bubble
#pragma unroll
      for (int i = 0; i < KNB; ++i) {
        const float lo = fminf(tk[i], d);
        d = fmaxf(tk[i], d);
        tk[i] = lo;
      }
    }
  }

  __shared__ float s_tk[256][KNB];
  __shared__ float s_T[64];
  __shared__ int   s_cnt[64];
  __shared__ int   s_mi[64][24];
  __shared__ float s_di[64][24];

#pragma unroll
  for (int i = 0; i < KNB; ++i) s_tk[t][i] = tk[i];
  if (t < 64) s_cnt[t] = 0;
  __syncthreads();

  if (q == 0) {  // 4-way merge -> T = 20th smallest distance for point n
    int i0 = 0, i1 = 0, i2 = 0, i3 = 0;
    float T = 0.f;
    for (int c = 0; c < KNB; ++c) {
      const float v0 = s_tk[lane][i0];
      const float v1 = s_tk[64 + lane][i1];
      const float v2 = s_tk[128 + lane][i2];
      const float v3 = s_tk[192 + lane][i3];
      T = fminf(fminf(v0, v1), fminf(v2, v3));
      if (T == v0) ++i0;
      else if (T == v1) ++i1;
      else if (T == v2) ++i2;
      else ++i3;
    }
    s_T[lane] = T;
  }
  __syncthreads();
  const float T = s_T[lane];

  // collect candidates with d <= T
  for (int m = mlo; m < mhi; ++m) {
    if (fl[m] == 0) continue;
    const float d0 = xb[m] - xn0;
    const float d1 = xb[NN + m] - xn1;
    const float d2 = xb[2 * NN + m] - xn2;
    const float d = __builtin_fmaf(d0, d0, __builtin_fmaf(d1, d1, d2 * d2));
    if (d <= T) {
      const int pos = atomicAdd(&s_cnt[lane], 1);
      if (pos < 24) { s_mi[lane][pos] = m; s_di[lane][pos] = d; }
    }
  }
  __syncthreads();

  if (q == 0) {
    const int cnt = min(s_cnt[lane], 24);
    // exact (d, m) insertion sort -> matches top_k tie-break (lower index first)
    for (int i = 1; i < cnt; ++i) {
      const float dk = s_di[lane][i];
      const int   mk = s_mi[lane][i];
      int j = i - 1;
      while (j >= 0 && (s_di[lane][j] > dk ||
                        (s_di[lane][j] == dk && s_mi[lane][j] > mk))) {
        s_di[lane][j + 1] = s_di[lane][j];
        s_mi[lane][j + 1] = s_mi[lane][j];
        --j;
      }
      s_di[lane][j + 1] = dk;
      s_mi[lane][j + 1] = mk;
    }
    const int kk = min(cnt, KNB);
    float mx = 0.f, my = 0.f, mz = 0.f;
#pragma unroll
    for (int j = 0; j < KNB; ++j) {
      if (j < kk) {
        const int mi = s_mi[lane][j];
        mx += xb[mi]; my += xb[NN + mi]; mz += xb[2 * NN + mi];
      }
    }
    const float inv = 1.0f / (float)max(kk, 1);
    mx *= inv; my *= inv; mz *= inv;
    float c00 = 0, c01 = 0, c02 = 0, c11 = 0, c12 = 0, c22 = 0;
#pragma unroll
    for (int j = 0; j < KNB; ++j) {
      if (j < kk) {
        const int mi = s_mi[lane][j];
        const float ax = xb[mi] - mx, ay = xb[NN + mi] - my, az = xb[2 * NN + mi] - mz;
        c00 += ax * ax; c01 += ax * ay; c02 += ax * az;
        c11 += ay * ay; c12 += ay * az; c22 += az * az;
      }
    }
    float* __restrict__ op = h0 + (size_t)b * 12 * NN + n;
    op[0] = xn0; op[(size_t)NN] = xn1; op[(size_t)2 * NN] = xn2;
    op[(size_t)3 * NN] = c00; op[(size_t)4 * NN]  = c01; op[(size_t)5 * NN]  = c02;
    op[(size_t)6 * NN] = c01; op[(size_t)7 * NN]  = c11; op[(size_t)8 * NN]  = c12;
    op[(size_t)9 * NN] = c02; op[(size_t)10 * NN] = c12; op[(size_t)11 * NN] = c22;
  }
}

// ---------------- stats: mo[c] = sum h[c], So[i][j] = sum h[i]h[j] (upper) ----------------
template <int C>
__global__ __launch_bounds__(256) void k_stats(const float* __restrict__ h,
                                               float* __restrict__ mo,
                                               float* __restrict__ So) {
  constexpr int NP  = C * (C + 1) / 2;
  constexpr int KPT = (NP + 255) / 256;
  __shared__ float tile[C][65];
  const int t = threadIdx.x;
  float acc[KPT];
#pragma unroll
  for (int e = 0; e < KPT; ++e) acc[e] = 0.f;
  float accm = 0.f;

  for (int tl = blockIdx.x; tl < BN_ / 64; tl += gridDim.x) {
    const int b  = tl >> 7;
    const int p0 = (tl & 127) * 64;
    for (int idx = t; idx < C * 64; idx += 256) {
      const int c = idx >> 6, p = idx & 63;
      tile[c][p] = h[((size_t)b * C + c) * NN + p0 + p];
    }
    __syncthreads();
    {
      int ii = 0, rem = t;   // incremental triangular decode
#pragma unroll
      for (int e = 0; e < KPT; ++e) {
        const int lin = t + 256 * e;
        if (lin < NP) {
          while (rem >= C - ii) { rem -= C - ii; ++ii; }
          const int jj = ii + rem;
          float s = 0.f;
#pragma unroll 8
          for (int p = 0; p < 64; ++p) s = __builtin_fmaf(tile[ii][p], tile[jj][p], s);
          acc[e] += s;
        }
        rem += 256;
      }
    }
    if (t < C) {
      float s = 0.f;
#pragma unroll 8
      for (int p = 0; p < 64; ++p) s += tile[t][p];
      accm += s;
    }
    __syncthreads();
  }
  {
    int ii = 0, rem = t;
#pragma unroll
    for (int e = 0; e < KPT; ++e) {
      const int lin = t + 256 * e;
      if (lin < NP) {
        while (rem >= C - ii) { rem -= C - ii; ++ii; }
        atomicAdd(&So[ii * C + ii + rem], acc[e]);
      }
      rem += 256;
    }
  }
  if (t < C) atomicAdd(&mo[t], accm);
}

// ---------------- solve BN affine: A = g/sigma, B = b - mu*g/sigma ----------------
template <int CIN, int COUT>
__global__ void k_solve(const float* __restrict__ w, const float* __restrict__ g,
                        const float* __restrict__ bb, const float* __restrict__ m,
                        const float* __restrict__ S, float* __restrict__ A,
                        float* __restrict__ Bc) {
  const int o = blockIdx.x * blockDim.x + threadIdx.x;
  if (o >= COUT) return;
  const float* wr = w + (size_t)o * CIN;
  float mu = 0.f;
  for (int c = 0; c < CIN; ++c) mu = __builtin_fmaf(wr[c], m[c], mu);
  mu *= (1.0f / BN_);
  float e2 = 0.f;
  for (int i = 0; i < CIN; ++i) {
    const float wi = wr[i];
    e2 = __builtin_fmaf(wi * wi, S[i * CIN + i], e2);
    float s = 0.f;
    for (int j = i + 1; j < CIN; ++j) s = __builtin_fmaf(wr[j], S[i * CIN + j], s);
    e2 = __builtin_fmaf(2.0f * wi, s, e2);
  }
  e2 *= (1.0f / BN_);
  const float var = e2 - mu * mu;
  const float a = g[o] / sqrtf(var + EPSV);
  A[o] = a;
  Bc[o] = bb[o] - mu * a;
}

// ---------------- conv 1x1 + BN + ReLU ----------------
template <int CIN, int COUT>
__global__ __launch_bounds__(256) void k_conv(const float* __restrict__ hin,
                                              const float* __restrict__ w,
                                              const float* __restrict__ A,
                                              const float* __restrict__ Bc,
                                              float* __restrict__ hout) {
  constexpr int J = COUT / 4;
  __shared__ float tin[CIN][64];
  __shared__ float tw[COUT][CIN];
  const int t = threadIdx.x;
  for (int idx = t; idx < COUT * CIN; idx += 256) tw[idx / CIN][idx % CIN] = w[idx];
  const int tl = blockIdx.x;     // 512 tiles
  const int b  = tl >> 7;
  const int p0 = (tl & 127) * 64;
  for (int idx = t; idx < CIN * 64; idx += 256) {
    const int c = idx >> 6, p = idx & 63;
    tin[c][p] = hin[((size_t)b * CIN + c) * NN + p0 + p];
  }
  __syncthreads();
  const int p  = t & 63;
  const int og = __builtin_amdgcn_readfirstlane(t >> 6);
  float acc[J];
#pragma unroll
  for (int j = 0; j < J; ++j) acc[j] = 0.f;
  for (int c = 0; c < CIN; ++c) {
    const float ic = tin[c][p];
#pragma unroll
    for (int j = 0; j < J; ++j) acc[j] = __builtin_fmaf(tw[og * J + j][c], ic, acc[j]);
  }
#pragma unroll
  for (int j = 0; j < J; ++j) {
    const int o = og * J + j;
    const float v = fmaxf(__builtin_fmaf(acc[j], A[o], Bc[o]), 0.f);
    hout[((size_t)b * COUT + o) * NN + p0 + p] = v;
  }
}

// ---------------- w5 transpose: wT[c][o] ----------------
__global__ void k_wt(const float* __restrict__ w5, float* __restrict__ wT) {
  const int idx = blockIdx.x * 256 + threadIdx.x;
  if (idx < 1024 * 128) {
    const int o = idx >> 7, c = idx & 127;
    wT[c * 1024 + o] = w5[idx];
  }
}

// ---------------- conv5 + BN5 + ReLU + global max-pool ----------------
__global__ __launch_bounds__(256) void k_conv5pool(const float* __restrict__ h4,
                                                   const float* __restrict__ wT,
                                                   const float* __restrict__ A,
                                                   const float* __restrict__ Bc,
                                                   float* __restrict__ pooled) {
  __shared__ float tin[128][64];
  const int t  = threadIdx.x;
  const int p  = t & 63;
  const int og = __builtin_amdgcn_readfirstlane(t >> 6);
  const int tl = blockIdx.x;
  const int b  = tl >> 7;
  const int p0 = (tl & 127) * 64;
  for (int idx = t; idx < 128 * 64; idx += 256) {
    const int c = idx >> 6, pp = idx & 63;
    tin[c][pp] = h4[((size_t)b * 128 + c) * NN + p0 + pp];
  }
  __syncthreads();
  for (int ch = 0; ch < 16; ++ch) {
    const int obase = og * 256 + ch * 16;
    float acc[16];
#pragma unroll
    for (int j = 0; j < 16; ++j) acc[j] = 0.f;
    for (int c = 0; c < 128; ++c) {
      const float ic = tin[c][p];
      const float* __restrict__ wrow = wT + c * 1024 + obase;  // uniform -> s_load
#pragma unroll
      for (int j = 0; j < 16; ++j) acc[j] = __builtin_fmaf(wrow[j], ic, acc[j]);
    }
#pragma unroll
    for (int j = 0; j < 16; ++j) {
      const int o = obase + j;
      float v = fmaxf(__builtin_fmaf(acc[j], A[o], Bc[o]), 0.f);
      v = fmaxf(v, __shfl_xor(v, 32, 64));
      v = fmaxf(v, __shfl_xor(v, 16, 64));
      v = fmaxf(v, __shfl_xor(v, 8, 64));
      v = fmaxf(v, __shfl_xor(v, 4, 64));
      v = fmaxf(v, __shfl_xor(v, 2, 64));
      v = fmaxf(v, __shfl_xor(v, 1, 64));
      if (p == 0) atomicMax((int*)pooled + (size_t)b * 1024 + o, __float_as_int(v));
    }
  }
}

// ---------------- head: FC1 + BN6(batch of 4) + ReLU ----------------
__global__ void k_head1(const float* __restrict__ pooled, const float* __restrict__ lw1,
                        const float* __restrict__ g6, const float* __restrict__ b6,
                        float* __restrict__ sh) {
  const int o = blockIdx.x * 64 + threadIdx.x;
  if (o >= 512) return;
  const float* wr = lw1 + (size_t)o * 1024;
  float y0 = 0, y1 = 0, y2 = 0, y3 = 0;
  for (int c = 0; c < 1024; ++c) {
    const float wv = wr[c];
    y0 = __builtin_fmaf(wv, pooled[c], y0);
    y1 = __builtin_fmaf(wv, pooled[1024 + c], y1);
    y2 = __builtin_fmaf(wv, pooled[2048 + c], y2);
    y3 = __builtin_fmaf(wv, pooled[3072 + c], y3);
  }
  const float mu = 0.25f * (y0 + y1 + y2 + y3);
  const float d0 = y0 - mu, d1 = y1 - mu, d2 = y2 - mu, d3 = y3 - mu;
  const float var = 0.25f * (d0 * d0 + d1 * d1 + d2 * d2 + d3 * d3);
  const float a = g6[o] / sqrtf(var + EPSV);
  const float bc = b6[o];
  sh[o]        = fmaxf(__builtin_fmaf(d0, a, bc), 0.f);
  sh[512 + o]  = fmaxf(__builtin_fmaf(d1, a, bc), 0.f);
  sh[1024 + o] = fmaxf(__builtin_fmaf(d2, a, bc), 0.f);
  sh[1536 + o] = fmaxf(__builtin_fmaf(d3, a, bc), 0.f);
}

// ---------------- head: FC2 ----------------
__global__ void k_head2(const float* __restrict__ sh, const float* __restrict__ lw2,
                        const float* __restrict__ lb2, float* __restrict__ out) {
  const int t = threadIdx.x;
  if (t >= 16) return;
  const int b = t >> 2, i = t & 3;
  float s = lb2[i];
  const float* wr = lw2 + (size_t)i * 512;
  for (int c = 0; c < 512; ++c) s = __builtin_fmaf(wr[c], sh[b * 512 + c], s);
  out[b * 4 + i] = s;
}

extern "C" void kernel_launch(void* const* d_in, const int* in_sizes, int n_in,
                              void* d_out, int out_size, void* d_ws, size_t ws_size,
                              hipStream_t stream) {
  (void)in_sizes; (void)n_in; (void)out_size; (void)ws_size;
  const float* x    = (const float*)d_in[0];
  const void*  lidx = d_in[1];
  const float* w1 = (const float*)d_in[3];
  const float* w2 = (const float*)d_in[4];
  const float* w3 = (const float*)d_in[5];
  const float* w4 = (const float*)d_in[6];
  const float* w5 = (const float*)d_in[7];
  const float* g1 = (const float*)d_in[8],  *b1 = (const float*)d_in[9];
  const float* g2 = (const float*)d_in[10], *b2 = (const float*)d_in[11];
  const float* g3 = (const float*)d_in[12], *b3 = (const float*)d_in[13];
  const float* g4 = (const float*)d_in[14], *b4 = (const float*)d_in[15];
  const float* g5 = (const float*)d_in[16], *b5 = (const float*)d_in[17];
  const float* lw1 = (const float*)d_in[18];
  const float* g6 = (const float*)d_in[19], *b6 = (const float*)d_in[20];
  const float* lw2 = (const float*)d_in[21], *lb2 = (const float*)d_in[22];
  float* out = (float*)d_out;
  float* ws  = (float*)d_ws;

  // zero stats + pooled region (deterministic per call)
  hipMemsetAsync(ws + OFF_M0, 0, (OFF_ZEND - OFF_M0) * sizeof(float), stream);

  k_prep<<<1, 256, 0, stream>>>((const int*)lidx, (int*)(ws + OFF_MODE),
                                (int*)(ws + OFF_FLAGS));
  k_knn<<<512, 256, 0, stream>>>(x, (const int*)(ws + OFF_FLAGS), ws + OFF_H0);

  k_stats<12><<<128, 256, 0, stream>>>(ws + OFF_H0, ws + OFF_M0, ws + OFF_S0);
  k_solve<12, 64><<<1, 64, 0, stream>>>(w1, g1, b1, ws + OFF_M0, ws + OFF_S0,
                                        ws + OFF_A1, ws + OFF_B1);
  k_conv<12, 64><<<512, 256, 0, stream>>>(ws + OFF_H0, w1, ws + OFF_A1, ws + OFF_B1,
                                          ws + OFF_H1);

  k_stats<64><<<128, 256, 0, stream>>>(ws + OFF_H1, ws + OFF_M1, ws + OFF_S1);
  k_solve<64, 64><<<1, 64, 0, stream>>>(w2, g2, b2, ws + OFF_M1, ws + OFF_S1,
                                        ws + OFF_A2, ws + OFF_B2);
  k_conv<64, 64><<<512, 256, 0, stream>>>(ws + OFF_H1, w2, ws + OFF_A2, ws + OFF_B2,
                                          ws + OFF_H2);

  k_stats<64><<<128, 256, 0, stream>>>(ws + OFF_H2, ws + OFF_M2, ws + OFF_S2);
  k_solve<64, 64><<<1, 64, 0, stream>>>(w3, g3, b3, ws + OFF_M2, ws + OFF_S2,
                                        ws + OFF_A3, ws + OFF_B3);
  k_conv<64, 64><<<512, 256, 0, stream>>>(ws + OFF_H2, w3, ws + OFF_A3, ws + OFF_B3,
                                          ws + OFF_H3);

  k_stats<64><<<128, 256, 0, stream>>>(ws + OFF_H3, ws + OFF_M3, ws + OFF_S3);
  k_solve<64, 128><<<2, 64, 0, stream>>>(w4, g4, b4, ws + OFF_M3, ws + OFF_S3,
                                         ws + OFF_A4, ws + OFF_B4);
  k_conv<64, 128><<<512, 256, 0, stream>>>(ws + OFF_H3, w4, ws + OFF_A4, ws + OFF_B4,
                                           ws + OFF_H4);

  k_stats<128><<<128, 256, 0, stream>>>(ws + OFF_H4, ws + OFF_M4, ws + OFF_S4);
  k_solve<128, 1024><<<16, 64, 0, stream>>>(w5, g5, b5, ws + OFF_M4, ws + OFF_S4,
                                            ws + OFF_A5, ws + OFF_B5);
  k_wt<<<512, 256, 0, stream>>>(w5, ws + OFF_WT);
  k_conv5pool<<<512, 256, 0, stream>>>(ws + OFF_H4, ws + OFF_WT, ws + OFF_A5,
                                       ws + OFF_B5, ws + OFF_POOL);

  k_head1<<<8, 64, 0, stream>>>(ws + OFF_POOL, lw1, g6, b6, ws + OFF_SH);
  k_head2<<<1, 64, 0, stream>>>(ws + OFF_SH, lw2, lb2, out);
}

// Round 2
// 1542.434 us; speedup vs baseline: 1.8627x; 1.8627x over previous
//
#include <hip/hip_runtime.h>

constexpr int BB = 4, NN = 8192, KNB = 20;
constexpr int BN_ = BB * NN; // 32768
constexpr float EPSV = 1e-5f;

// ---------------- workspace layout (float offsets) ----------------
constexpr size_t OFF_MODE  = 0;
constexpr size_t OFF_FLAGS = 64;                    // int[4*8192]
constexpr size_t OFF_M0 = OFF_FLAGS + BN_;          // 32832  (zero region start)
constexpr size_t OFF_S0 = OFF_M0 + 12;
constexpr size_t OFF_M1 = OFF_S0 + 144;
constexpr size_t OFF_S1 = OFF_M1 + 64;
constexpr size_t OFF_M2 = OFF_S1 + 64 * 64;
constexpr size_t OFF_S2 = OFF_M2 + 64;
constexpr size_t OFF_M3 = OFF_S2 + 64 * 64;
constexpr size_t OFF_S3 = OFF_M3 + 64;
constexpr size_t OFF_M4 = OFF_S3 + 64 * 64;
constexpr size_t OFF_S4 = OFF_M4 + 128;
constexpr size_t OFF_POOL = OFF_S4 + 128 * 128;
constexpr size_t OFF_ZEND = OFF_POOL + BB * 1024;   // zero region end
constexpr size_t OFF_A1 = OFF_ZEND;
constexpr size_t OFF_B1 = OFF_A1 + 64;
constexpr size_t OFF_A2 = OFF_B1 + 64;
constexpr size_t OFF_B2 = OFF_A2 + 64;
constexpr size_t OFF_A3 = OFF_B2 + 64;
constexpr size_t OFF_B3 = OFF_A3 + 64;
constexpr size_t OFF_A4 = OFF_B3 + 64;
constexpr size_t OFF_B4 = OFF_A4 + 128;
constexpr size_t OFF_A5 = OFF_B4 + 128;
constexpr size_t OFF_B5 = OFF_A5 + 1024;
constexpr size_t OFF_SH = OFF_B5 + 1024;            // 4*512
constexpr size_t OFF_WT_RAW = OFF_SH + BB * 512;
constexpr size_t OFF_WT = (OFF_WT_RAW + 63) & ~size_t(63);  // wT5 [128][1024]
constexpr size_t OFF_H0_RAW = OFF_WT + 1024 * 128;
constexpr size_t OFF_H0 = (OFF_H0_RAW + 63) & ~size_t(63);  // [4][12][8192]
constexpr size_t OFF_H1 = OFF_H0 + (size_t)BB * 12 * NN;    // [4][64][8192]
constexpr size_t OFF_H2 = OFF_H1 + (size_t)BB * 64 * NN;    // [4][64][8192]
constexpr size_t OFF_H3 = OFF_H1;                           // alias (h1 dead)
constexpr size_t OFF_H4 = OFF_H2 + (size_t)BB * 64 * NN;    // [4][128][8192]
constexpr size_t WS_FLOATS = OFF_H4 + (size_t)BB * 128 * NN;

// ---------------- prep: detect bool storage + canonicalize flags ----------------
__global__ void k_prep(const int* __restrict__ li32, int* __restrict__ mode,
                       int* __restrict__ flags) {
  __shared__ int s_mode;
  const int t = threadIdx.x;
  if (t == 0) s_mode = 0;
  __syncthreads();
  // 8192 int32 = 32768 bytes: in-bounds under both interpretations.
  for (int i = t; i < 8192; i += 256)
    if (((const unsigned int*)li32)[i] > 1u) atomicOr(&s_mode, 1);
  __syncthreads();
  const int md = s_mode;   // 1 => stored as bytes, 0 => stored as int32
  if (t == 0) *mode = md;
  const unsigned char* p8 = (const unsigned char*)li32;
  for (int i = t; i < BN_; i += 256)
    flags[i] = md ? (p8[i] != 0 ? 1 : 0) : (li32[i] != 0 ? 1 : 0);
}

// ---------------- kNN + covariance -> h0 [4][12][8192] ----------------
__global__ __launch_bounds__(256) void k_knn(const float* __restrict__ x,
                                             const int* __restrict__ flags,
                                             float* __restrict__ h0) {
  const int blk  = blockIdx.x;        // 512 blocks = 4 batches * 128 tiles
  const int b    = blk >> 7;
  const int tile = blk & 127;
  const int t    = threadIdx.x;
  const int lane = t & 63;
  const int q    = __builtin_amdgcn_readfirstlane(t >> 6);  // m-quarter per wave
  const int n    = tile * 64 + lane;

  const float* __restrict__ xb = x + (size_t)b * 3 * NN;
  const int* __restrict__ fl = flags + b * NN;

  const float xn0 = xb[n], xn1 = xb[NN + n], xn2 = xb[2 * NN + n];

  float tk[KNB];
#pragma unroll
  for (int i = 0; i < KNB; ++i) tk[i] = 3.0e38f;

  const int mlo = q * (NN / 4), mhi = mlo + NN / 4;
  for (int m = mlo; m < mhi; ++m) {
    if (fl[m] == 0) continue;                       // wave-uniform skip
    const float d0 = xb[m] - xn0;
    const float d1 = xb[NN + m] - xn1;
    const float d2 = xb[2 * NN + m] - xn2;
    float d = __builtin_fmaf(d0, d0, __builtin_fmaf(d1, d1, d2 * d2));
    if (d < tk[KNB - 1]) {                          // sorted-insert bubble
#pragma unroll
      for (int i = 0; i < KNB; ++i) {
        const float lo = fminf(tk[i], d);
        d = fmaxf(tk[i], d);
        tk[i] = lo;
      }
    }
  }

  __shared__ float s_tk[256][KNB];
  __shared__ float s_T[64];
  __shared__ int   s_cnt[64];
  __shared__ int   s_mi[64][24];
  __shared__ float s_di[64][24];

#pragma unroll
  for (int i = 0; i < KNB; ++i) s_tk[t][i] = tk[i];
  if (t < 64) s_cnt[t] = 0;
  __syncthreads();

  if (q == 0) {  // 4-way merge -> T = 20th smallest distance for point n
    int i0 = 0, i1 = 0, i2 = 0, i3 = 0;
    float T = 0.f;
    for (int c = 0; c < KNB; ++c) {
      const float v0 = s_tk[lane][i0];
      const float v1 = s_tk[64 + lane][i1];
      const float v2 = s_tk[128 + lane][i2];
      const float v3 = s_tk[192 + lane][i3];
      T = fminf(fminf(v0, v1), fminf(v2, v3));
      if (T == v0) ++i0;
      else if (T == v1) ++i1;
      else if (T == v2) ++i2;
      else ++i3;
    }
    s_T[lane] = T;
  }
  __syncthreads();
  const float T = s_T[lane];

  // collect candidates with d <= T
  for (int m = mlo; m < mhi; ++m) {
    if (fl[m] == 0) continue;
    const float d0 = xb[m] - xn0;
    const float d1 = xb[NN + m] - xn1;
    const float d2 = xb[2 * NN + m] - xn2;
    const float d = __builtin_fmaf(d0, d0, __builtin_fmaf(d1, d1, d2 * d2));
    if (d <= T) {
      const int pos = atomicAdd(&s_cnt[lane], 1);
      if (pos < 24) { s_mi[lane][pos] = m; s_di[lane][pos] = d; }
    }
  }
  __syncthreads();

  if (q == 0) {
    const int cnt = min(s_cnt[lane], 24);
    // exact (d, m) insertion sort -> matches top_k tie-break (lower index first)
    for (int i = 1; i < cnt; ++i) {
      const float dk = s_di[lane][i];
      const int   mk = s_mi[lane][i];
      int j = i - 1;
      while (j >= 0 && (s_di[lane][j] > dk ||
                        (s_di[lane][j] == dk && s_mi[lane][j] > mk))) {
        s_di[lane][j + 1] = s_di[lane][j];
        s_mi[lane][j + 1] = s_mi[lane][j];
        --j;
      }
      s_di[lane][j + 1] = dk;
      s_mi[lane][j + 1] = mk;
    }
    const int kk = min(cnt, KNB);
    float mx = 0.f, my = 0.f, mz = 0.f;
#pragma unroll
    for (int j = 0; j < KNB; ++j) {
      if (j < kk) {
        const int mi = s_mi[lane][j];
        mx += xb[mi]; my += xb[NN + mi]; mz += xb[2 * NN + mi];
      }
    }
    const float inv = 1.0f / (float)max(kk, 1);
    mx *= inv; my *= inv; mz *= inv;
    float c00 = 0, c01 = 0, c02 = 0, c11 = 0, c12 = 0, c22 = 0;
#pragma unroll
    for (int j = 0; j < KNB; ++j) {
      if (j < kk) {
        const int mi = s_mi[lane][j];
        const float ax = xb[mi] - mx, ay = xb[NN + mi] - my, az = xb[2 * NN + mi] - mz;
        c00 += ax * ax; c01 += ax * ay; c02 += ax * az;
        c11 += ay * ay; c12 += ay * az; c22 += az * az;
      }
    }
    float* __restrict__ op = h0 + (size_t)b * 12 * NN + n;
    op[0] = xn0; op[(size_t)NN] = xn1; op[(size_t)2 * NN] = xn2;
    op[(size_t)3 * NN] = c00; op[(size_t)4 * NN]  = c01; op[(size_t)5 * NN]  = c02;
    op[(size_t)6 * NN] = c01; op[(size_t)7 * NN]  = c11; op[(size_t)8 * NN]  = c12;
    op[(size_t)9 * NN] = c02; op[(size_t)10 * NN] = c12; op[(size_t)11 * NN] = c22;
  }
}

// ---------------- stats: mo[c] = sum h[c], So[i][j] = sum h[i]h[j] (upper) ----------------
template <int C>
__global__ __launch_bounds__(256) void k_stats(const float* __restrict__ h,
                                               float* __restrict__ mo,
                                               float* __restrict__ So) {
  constexpr int NP  = C * (C + 1) / 2;
  constexpr int KPT = (NP + 255) / 256;
  __shared__ float tile[C][65];
  const int t = threadIdx.x;
  float acc[KPT];
#pragma unroll
  for (int e = 0; e < KPT; ++e) acc[e] = 0.f;
  float accm = 0.f;

  for (int tl = blockIdx.x; tl < BN_ / 64; tl += gridDim.x) {
    const int b  = tl >> 7;
    const int p0 = (tl & 127) * 64;
    for (int idx = t; idx < C * 64; idx += 256) {
      const int c = idx >> 6, p = idx & 63;
      tile[c][p] = h[((size_t)b * C + c) * NN + p0 + p];
    }
    __syncthreads();
    {
      int ii = 0, rem = t;   // incremental triangular decode
#pragma unroll
      for (int e = 0; e < KPT; ++e) {
        const int lin = t + 256 * e;
        if (lin < NP) {
          while (rem >= C - ii) { rem -= C - ii; ++ii; }
          const int jj = ii + rem;
          float s = 0.f;
#pragma unroll 8
          for (int p = 0; p < 64; ++p) s = __builtin_fmaf(tile[ii][p], tile[jj][p], s);
          acc[e] += s;
        }
        rem += 256;
      }
    }
    if (t < C) {
      float s = 0.f;
#pragma unroll 8
      for (int p = 0; p < 64; ++p) s += tile[t][p];
      accm += s;
    }
    __syncthreads();
  }
  {
    int ii = 0, rem = t;
#pragma unroll
    for (int e = 0; e < KPT; ++e) {
      const int lin = t + 256 * e;
      if (lin < NP) {
        while (rem >= C - ii) { rem -= C - ii; ++ii; }
        atomicAdd(&So[ii * C + ii + rem], acc[e]);
      }
      rem += 256;
    }
  }
  if (t < C) atomicAdd(&mo[t], accm);
}

// ---------------- solve BN affine: A = g/sigma, B = b - mu*g/sigma ----------------
// One wave per output channel; lanes split the CIN x CIN quadratic form
// (symmetric fetch from the upper-triangular S), shuffle-reduce.
template <int CIN, int COUT>
__global__ __launch_bounds__(256) void k_solve(const float* __restrict__ w, const float* __restrict__ g,
                        const float* __restrict__ bb, const float* __restrict__ m,
                        const float* __restrict__ S, float* __restrict__ A,
                        float* __restrict__ Bc) {
  const int wv   = threadIdx.x >> 6;
  const int lane = threadIdx.x & 63;
  const int o    = blockIdx.x * 4 + wv;
  if (o >= COUT) return;
  const float* __restrict__ wr = w + (size_t)o * CIN;
  float mu = 0.f;
  for (int i = lane; i < CIN; i += 64) mu = __builtin_fmaf(wr[i], m[i], mu);
  float e2 = 0.f;
  for (int lin = lane; lin < CIN * CIN; lin += 64) {
    const int i = lin / CIN;
    const int j = lin - i * CIN;
    const int lo = min(i, j), hi = max(i, j);
    e2 = __builtin_fmaf(wr[i] * wr[j], S[lo * CIN + hi], e2);
  }
#pragma unroll
  for (int off = 32; off >= 1; off >>= 1) {
    mu += __shfl_xor(mu, off, 64);
    e2 += __shfl_xor(e2, off, 64);
  }
  if (lane == 0) {
    mu *= (1.0f / BN_);
    e2 *= (1.0f / BN_);
    const float var = e2 - mu * mu;
    const float a = g[o] / sqrtf(var + EPSV);
    A[o] = a;
    Bc[o] = bb[o] - mu * a;
  }
}

// ---------------- conv 1x1 + BN + ReLU ----------------
template <int CIN, int COUT>
__global__ __launch_bounds__(256) void k_conv(const float* __restrict__ hin,
                                              const float* __restrict__ w,
                                              const float* __restrict__ A,
                                              const float* __restrict__ Bc,
                                              float* __restrict__ hout) {
  constexpr int J = COUT / 4;
  __shared__ float tin[CIN][64];
  __shared__ float tw[COUT][CIN];
  const int t = threadIdx.x;
  for (int idx = t; idx < COUT * CIN; idx += 256) tw[idx / CIN][idx % CIN] = w[idx];
  const int tl = blockIdx.x;     // 512 tiles
  const int b  = tl >> 7;
  const int p0 = (tl & 127) * 64;
  for (int idx = t; idx < CIN * 64; idx += 256) {
    const int c = idx >> 6, p = idx & 63;
    tin[c][p] = hin[((size_t)b * CIN + c) * NN + p0 + p];
  }
  __syncthreads();
  const int p  = t & 63;
  const int og = __builtin_amdgcn_readfirstlane(t >> 6);
  float acc[J];
#pragma unroll
  for (int j = 0; j < J; ++j) acc[j] = 0.f;
  for (int c = 0; c < CIN; ++c) {
    const float ic = tin[c][p];
#pragma unroll
    for (int j = 0; j < J; ++j) acc[j] = __builtin_fmaf(tw[og * J + j][c], ic, acc[j]);
  }
#pragma unroll
  for (int j = 0; j < J; ++j) {
    const int o = og * J + j;
    const float v = fmaxf(__builtin_fmaf(acc[j], A[o], Bc[o]), 0.f);
    hout[((size_t)b * COUT + o) * NN + p0 + p] = v;
  }
}

// ---------------- w5 transpose: wT[c][o] ----------------
__global__ void k_wt(const float* __restrict__ w5, float* __restrict__ wT) {
  const int idx = blockIdx.x * 256 + threadIdx.x;
  if (idx < 1024 * 128) {
    const int o = idx >> 7, c = idx & 127;
    wT[c * 1024 + o] = w5[idx];
  }
}

// ---------------- conv5 + BN5 + ReLU + global max-pool ----------------
__global__ __launch_bounds__(256) void k_conv5pool(const float* __restrict__ h4,
                                                   const float* __restrict__ wT,
                                                   const float* __restrict__ A,
                                                   const float* __restrict__ Bc,
                                                   float* __restrict__ pooled) {
  __shared__ float tin[128][64];
  const int t  = threadIdx.x;
  const int p  = t & 63;
  const int og = __builtin_amdgcn_readfirstlane(t >> 6);
  const int tl = blockIdx.x;
  const int b  = tl >> 7;
  const int p0 = (tl & 127) * 64;
  for (int idx = t; idx < 128 * 64; idx += 256) {
    const int c = idx >> 6, pp = idx & 63;
    tin[c][pp] = h4[((size_t)b * 128 + c) * NN + p0 + pp];
  }
  __syncthreads();
  for (int ch = 0; ch < 16; ++ch) {
    const int obase = og * 256 + ch * 16;
    float acc[16];
#pragma unroll
    for (int j = 0; j < 16; ++j) acc[j] = 0.f;
    for (int c = 0; c < 128; ++c) {
      const float ic = tin[c][p];
      const float* __restrict__ wrow = wT + c * 1024 + obase;  // uniform -> s_load
#pragma unroll
      for (int j = 0; j < 16; ++j) acc[j] = __builtin_fmaf(wrow[j], ic, acc[j]);
    }
#pragma unroll
    for (int j = 0; j < 16; ++j) {
      const int o = obase + j;
      float v = fmaxf(__builtin_fmaf(acc[j], A[o], Bc[o]), 0.f);
      v = fmaxf(v, __shfl_xor(v, 32, 64));
      v = fmaxf(v, __shfl_xor(v, 16, 64));
      v = fmaxf(v, __shfl_xor(v, 8, 64));
      v = fmaxf(v, __shfl_xor(v, 4, 64));
      v = fmaxf(v, __shfl_xor(v, 2, 64));
      v = fmaxf(v, __shfl_xor(v, 1, 64));
      if (p == 0) atomicMax((int*)pooled + (size_t)b * 1024 + o, __float_as_int(v));
    }
  }
}

// ---------------- head: FC1 + BN6(batch of 4) + ReLU ----------------
// One wave per output o; lanes split the 1024-dim dot product (coalesced).
__global__ __launch_bounds__(256) void k_head1(const float* __restrict__ pooled, const float* __restrict__ lw1,
                        const float* __restrict__ g6, const float* __restrict__ b6,
                        float* __restrict__ sh) {
  const int wv   = threadIdx.x >> 6;
  const int lane = threadIdx.x & 63;
  const int o    = blockIdx.x * 4 + wv;    // grid 128
  const float* __restrict__ wr = lw1 + (size_t)o * 1024;
  float y0 = 0, y1 = 0, y2 = 0, y3 = 0;
  for (int c = lane; c < 1024; c += 64) {
    const float wvv = wr[c];
    y0 = __builtin_fmaf(wvv, pooled[c], y0);
    y1 = __builtin_fmaf(wvv, pooled[1024 + c], y1);
    y2 = __builtin_fmaf(wvv, pooled[2048 + c], y2);
    y3 = __builtin_fmaf(wvv, pooled[3072 + c], y3);
  }
#pragma unroll
  for (int off = 32; off >= 1; off >>= 1) {
    y0 += __shfl_xor(y0, off, 64);
    y1 += __shfl_xor(y1, off, 64);
    y2 += __shfl_xor(y2, off, 64);
    y3 += __shfl_xor(y3, off, 64);
  }
  if (lane == 0) {
    const float mu = 0.25f * (y0 + y1 + y2 + y3);
    const float d0 = y0 - mu, d1 = y1 - mu, d2 = y2 - mu, d3 = y3 - mu;
    const float var = 0.25f * (d0 * d0 + d1 * d1 + d2 * d2 + d3 * d3);
    const float a = g6[o] / sqrtf(var + EPSV);
    const float bc = b6[o];
    sh[o]        = fmaxf(__builtin_fmaf(d0, a, bc), 0.f);
    sh[512 + o]  = fmaxf(__builtin_fmaf(d1, a, bc), 0.f);
    sh[1024 + o] = fmaxf(__builtin_fmaf(d2, a, bc), 0.f);
    sh[1536 + o] = fmaxf(__builtin_fmaf(d3, a, bc), 0.f);
  }
}

// ---------------- head: FC2 ----------------
// One wave per batch element; lanes split c, shuffle-reduce 4 outputs.
__global__ void k_head2(const float* __restrict__ sh, const float* __restrict__ lw2,
                        const float* __restrict__ lb2, float* __restrict__ out) {
  const int wv   = threadIdx.x >> 6;  // = b (4 waves)
  const int lane = threadIdx.x & 63;
  float s0 = 0, s1 = 0, s2 = 0, s3 = 0;
  for (int c = lane; c < 512; c += 64) {
    const float h = sh[wv * 512 + c];
    s0 = __builtin_fmaf(lw2[c], h, s0);
    s1 = __builtin_fmaf(lw2[512 + c], h, s1);
    s2 = __builtin_fmaf(lw2[1024 + c], h, s2);
    s3 = __builtin_fmaf(lw2[1536 + c], h, s3);
  }
#pragma unroll
  for (int off = 32; off >= 1; off >>= 1) {
    s0 += __shfl_xor(s0, off, 64);
    s1 += __shfl_xor(s1, off, 64);
    s2 += __shfl_xor(s2, off, 64);
    s3 += __shfl_xor(s3, off, 64);
  }
  if (lane == 0) {
    out[wv * 4 + 0] = s0 + lb2[0];
    out[wv * 4 + 1] = s1 + lb2[1];
    out[wv * 4 + 2] = s2 + lb2[2];
    out[wv * 4 + 3] = s3 + lb2[3];
  }
}

extern "C" void kernel_launch(void* const* d_in, const int* in_sizes, int n_in,
                              void* d_out, int out_size, void* d_ws, size_t ws_size,
                              hipStream_t stream) {
  (void)in_sizes; (void)n_in; (void)out_size; (void)ws_size;
  const float* x    = (const float*)d_in[0];
  const void*  lidx = d_in[1];
  const float* w1 = (const float*)d_in[3];
  const float* w2 = (const float*)d_in[4];
  const float* w3 = (const float*)d_in[5];
  const float* w4 = (const float*)d_in[6];
  const float* w5 = (const float*)d_in[7];
  const float* g1 = (const float*)d_in[8],  *b1 = (const float*)d_in[9];
  const float* g2 = (const float*)d_in[10], *b2 = (const float*)d_in[11];
  const float* g3 = (const float*)d_in[12], *b3 = (const float*)d_in[13];
  const float* g4 = (const float*)d_in[14], *b4 = (const float*)d_in[15];
  const float* g5 = (const float*)d_in[16], *b5 = (const float*)d_in[17];
  const float* lw1 = (const float*)d_in[18];
  const float* g6 = (const float*)d_in[19], *b6 = (const float*)d_in[20];
  const float* lw2 = (const float*)d_in[21], *lb2 = (const float*)d_in[22];
  float* out = (float*)d_out;
  float* ws  = (float*)d_ws;

  // zero stats + pooled region (deterministic per call)
  hipMemsetAsync(ws + OFF_M0, 0, (OFF_ZEND - OFF_M0) * sizeof(float), stream);

  k_prep<<<1, 256, 0, stream>>>((const int*)lidx, (int*)(ws + OFF_MODE),
                                (int*)(ws + OFF_FLAGS));
  k_knn<<<512, 256, 0, stream>>>(x, (const int*)(ws + OFF_FLAGS), ws + OFF_H0);

  k_stats<12><<<128, 256, 0, stream>>>(ws + OFF_H0, ws + OFF_M0, ws + OFF_S0);
  k_solve<12, 64><<<16, 256, 0, stream>>>(w1, g1, b1, ws + OFF_M0, ws + OFF_S0,
                                          ws + OFF_A1, ws + OFF_B1);
  k_conv<12, 64><<<512, 256, 0, stream>>>(ws + OFF_H0, w1, ws + OFF_A1, ws + OFF_B1,
                                          ws + OFF_H1);

  k_stats<64><<<128, 256, 0, stream>>>(ws + OFF_H1, ws + OFF_M1, ws + OFF_S1);
  k_solve<64, 64><<<16, 256, 0, stream>>>(w2, g2, b2, ws + OFF_M1, ws + OFF_S1,
                                          ws + OFF_A2, ws + OFF_B2);
  k_conv<64, 64><<<512, 256, 0, stream>>>(ws + OFF_H1, w2, ws + OFF_A2, ws + OFF_B2,
                                          ws + OFF_H2);

  k_stats<64><<<128, 256, 0, stream>>>(ws + OFF_H2, ws + OFF_M2, ws + OFF_S2);
  k_solve<64, 64><<<16, 256, 0, stream>>>(w3, g3, b3, ws + OFF_M2, ws + OFF_S2,
                                          ws + OFF_A3, ws + OFF_B3);
  k_conv<64, 64><<<512, 256, 0, stream>>>(ws + OFF_H2, w3, ws + OFF_A3, ws + OFF_B3,
                                          ws + OFF_H3);

  k_stats<64><<<128, 256, 0, stream>>>(ws + OFF_H3, ws + OFF_M3, ws + OFF_S3);
  k_solve<64, 128><<<32, 256, 0, stream>>>(w4, g4, b4, ws + OFF_M3, ws + OFF_S3,
                                           ws + OFF_A4, ws + OFF_B4);
  k_conv<64, 128><<<512, 256, 0, stream>>>(ws + OFF_H3, w4, ws + OFF_A4, ws + OFF_B4,
                                           ws + OFF_H4);

  k_stats<128><<<128, 256, 0, stream>>>(ws + OFF_H4, ws + OFF_M4, ws + OFF_S4);
  k_solve<128, 1024><<<256, 256, 0, stream>>>(w5, g5, b5, ws + OFF_M4, ws + OFF_S4,
                                              ws + OFF_A5, ws + OFF_B5);
  k_wt<<<512, 256, 0, stream>>>(w5, ws + OFF_WT);
  k_conv5pool<<<512, 256, 0, stream>>>(ws + OFF_H4, ws + OFF_WT, ws + OFF_A5,
                                       ws + OFF_B5, ws + OFF_POOL);

  k_head1<<<128, 256, 0, stream>>>(ws + OFF_POOL, lw1, g6, b6, ws + OFF_SH);
  k_head2<<<1, 256, 0, stream>>>(ws + OFF_SH, lw2, lb2, out);
}